// Round 9
// baseline (226.909 us; speedup 1.0000x reference)
//
#include <hip/hip_runtime.h>
#include <math.h>

typedef unsigned short u16;
using bf16x8 = __attribute__((ext_vector_type(8))) short;
using f32x4  = __attribute__((ext_vector_type(4))) float;

#define NS      128
#define RAYS_PER_BLOCK 2
#define NBLOCKS (4096 / RAYS_PER_BLOCK)   // 2048 blocks
#define KS1     15      // 30 channels * 16 slots = 480 K
#define NSLICE  19      // 15 (W1) + 4 (W2) unified W slices of 4096 u16

// LDS pool offsets (u16 units). X slices are in MFMA-A-frag order (4096 u16
// each, padless). h1/h2 (A-frag order, 32 KB) OVERLAY the X double-buffer;
// part[] overlays the W double-buffer after the K-loop.
#define OW0   0         // W buf 0: 4096 u16
#define OW1   4096      // W buf 1: 4096 u16
#define OX0   8192      // X slice buf 0: 4096 u16 (frag order)
#define OX1   12288     // X slice buf 1: 4096 u16
#define OH1   8192      // h1/h2 frag-order: 128*128 = 16384 u16 (overlays X0+X1)
#define POOLSZ 24576    // 49152 B -> 3 blocks/CU

__device__ __forceinline__ u16 f2bf(float f) {           // host-prep path only
    unsigned int i = __float_as_uint(f);
    return (u16)((i + 0x7FFFu + ((i >> 16) & 1u)) >> 16);  // RNE
}

// pack two floats to bf16 pair [hi:lo] in one dword (round half away + perm)
__device__ __forceinline__ unsigned pk(float hi, float lo) {
    unsigned a = __float_as_uint(hi) + 0x8000u;
    unsigned b = __float_as_uint(lo) + 0x8000u;
    return __builtin_amdgcn_perm(a, b, 0x07060302u);  // [a.hi16 : b.hi16]
}
__device__ __forceinline__ u16 f2bf1(float f) {
    return (u16)((__float_as_uint(f) + 0x8000u) >> 16);
}

// A-frag-order offset for a [128 x K] bf16 matrix (k-slices of 32 are 4096 u16
// each; a wave A-frag ds_read_b128 is lane-sequential, conflict-free):
__device__ __forceinline__ int afoff(int m, int k) {
    return ((((k >> 5) * 8 + (m >> 4)) * 64) + (((k >> 3) & 3) * 16) + (m & 15)) * 8 + (k & 7);
}

// async global->LDS copy of one 8 KB W slice (no VGPR round-trip).
__device__ __forceinline__ void stage_w(const u16* g, u16* l, int wave, int lane) {
    #pragma unroll
    for (int c = 0; c < 2; ++c) {
        const u16* gp = g + (wave * 2 + c) * 512 + lane * 8;
        u16* lp = l + (wave * 2 + c) * 512;
        __builtin_amdgcn_global_load_lds(
            (const __attribute__((address_space(1))) unsigned int*)gp,
            (__attribute__((address_space(3))) unsigned int*)lp, 16, 0, 0);
    }
}

// channel/slot -> original mlp_in k index (reference ordering)
__device__ __forceinline__ int orig_k(int ch, int slot) {
    if (ch < 27) {
        if (slot == 0) return ch;
        if (slot <= 6) return 30 + ch * 6 + (slot - 1);     // sin(app)
        return 192 + ch * 6 + (slot - 7);                    // cos(app)
    } else {
        int c = ch - 27;
        if (slot == 0) return 27 + c;
        if (slot <= 6) return 354 + c * 6 + (slot - 1);      // sin(view)
        return 372 + c * 6 + (slot - 7);                     // cos(view)
    }
}

// build one channel-half of a frag-order X slice: thread (m_b, cl_b) owns
// chunks 2cl_b, 2cl_b+1 of group g=m_b>>4; slots [v, sin f0..5, cos f0..5, 0x3]
__device__ __forceinline__ void build_x(u16* Xb, int m_b, int cl_b, float v) {
    float rev = v * 0.15915494309189535f;
    rev -= floorf(rev);
    float s0 = __builtin_amdgcn_sinf(rev);
    float c0 = __builtin_amdgcn_cosf(rev);
    float s1 = 2.f * s0 * c0, c1 = c0 * c0 - s0 * s0;
    float s2 = 2.f * s1 * c1, c2 = c1 * c1 - s1 * s1;
    float s3 = 2.f * s2 * c2, c3 = c2 * c2 - s2 * s2;
    float s4 = 2.f * s3 * c3, c4 = c3 * c3 - s3 * s3;
    float s5 = 2.f * s4 * c4, c5 = c4 * c4 - s4 * s4;
    uint4 lo, hi;
    lo.x = pk(s0, v);  lo.y = pk(s2, s1);  lo.z = pk(s4, s3);  lo.w = pk(c0, s5);
    hi.x = pk(c2, c1); hi.y = pk(c4, c3);  hi.z = pk(0.f, c5); hi.w = 0u;
    int base = (m_b >> 4) * 512 + ((2 * cl_b) * 16 + (m_b & 15)) * 8;
    *(uint4*)(Xb + base)       = lo;   // chunk 2*cl_b
    *(uint4*)(Xb + base + 128) = hi;   // chunk 2*cl_b+1 (+16*8 u16)
}

// W1 -> 15 slices, W2 -> 4 slices, W3 -> 4 mini B-frag slices (N padded 16)
__global__ __launch_bounds__(256) void prep_kernel(
    const float* __restrict__ W1, const float* __restrict__ W2,
    const float* __restrict__ W3, u16* __restrict__ ws)
{
    int idx = blockIdx.x * 256 + threadIdx.x;
    if (idx < 61440) {                               // W1r: [ks15][nt8][lane64][j8]
        int j = idx & 7, lane = (idx >> 3) & 63, nt = (idx >> 9) & 7, ks = idx >> 12;
        int q = lane >> 4, l15 = lane & 15;
        int klocal = q * 8 + j;                      // 0..31
        int ch = ks * 2 + (klocal >> 4);
        int slot = klocal & 15;
        int n = nt * 16 + l15;
        ws[idx] = (slot < 13) ? f2bf(W1[orig_k(ch, slot) * 128 + n]) : (u16)0;
    } else if (idx < 77824) {                        // W2r: [ks4][nt8][lane64][j8]
        int i2 = idx - 61440;
        int j = i2 & 7, lane = (i2 >> 3) & 63, nt = (i2 >> 9) & 7, ks = i2 >> 12;
        int k = ks * 32 + (lane >> 4) * 8 + j;
        int n = nt * 16 + (lane & 15);
        ws[idx] = f2bf(W2[k * 128 + n]);
    } else if (idx < 79872) {                        // W3r: [ks4][lane64][j8], N pad 16
        int i3 = idx - 77824;
        int j = i3 & 7, lane = (i3 >> 3) & 63, ks = i3 >> 9;
        int k = ks * 32 + (lane >> 4) * 8 + j;
        int n = lane & 15;
        ws[idx] = (n < 3) ? f2bf(W3[k * 3 + n]) : (u16)0;
    }
}

__global__ __launch_bounds__(256, 3) void render_kernel(
    const float* __restrict__ sigma_g, const float* __restrict__ app_g,
    const float* __restrict__ view_g,  const float* __restrict__ dists_g,
    const float* __restrict__ b1_g,    const float* __restrict__ b2_g,
    const float* __restrict__ b3_g,    const u16* __restrict__ ws,
    float* __restrict__ out_g)
{
    __shared__ __align__(16) u16 pool[POOLSZ];
    __shared__ float scanS;          // wave0 scan total broadcast
    __shared__ float sum2[6];        // per-wave final partials
    float* part = (float*)(pool + OW0);   // [NS*3] overlays W dbuf (dead post K-loop)

    const int tid  = threadIdx.x;
    const int lane = tid & 63;
    const int wave = tid >> 6;
    const int l15  = lane & 15;
    const int quad = lane >> 4;
    const int wm   = wave >> 1;      // row half
    const int wn   = wave & 1;       // col half

    const u16* w3r = ws + 77824;

    // per-kernel constants in registers
    float b1r[4], b2r[4];
    #pragma unroll
    for (int nt = 0; nt < 4; ++nt) {
        int col = wn * 64 + nt * 16 + l15;
        b1r[nt] = b1_g[col];
        b2r[nt] = b2_g[col];
    }
    const float b3v = (l15 < 3) ? b3_g[l15] : 0.f;
    bf16x8 w3fr[4];
    #pragma unroll
    for (int ks = 0; ks < 4; ++ks)
        w3fr[ks] = *(const bf16x8*)(w3r + (ks * 64 + lane) * 8);

    const int m_b  = tid >> 1;       // X-build row
    const int cl_b = tid & 1;        // X-build channel-local

    #pragma unroll 1
    for (int ri = 0; ri < RAYS_PER_BLOCK; ++ri) {
        const int r  = blockIdx.x * RAYS_PER_BLOCK + ri;
        const int rb = r * NS;

        // ---- prefetch this thread's 15 input channel values (one drain/ray) ----
        float pv[15];
        {
            const float* ap = app_g  + (rb + m_b) * 27;
            const float* vp = view_g + (rb + m_b) * 3;
            #pragma unroll
            for (int i = 0; i < 15; ++i) {
                int ch = 2 * i + cl_b;
                pv[i] = (ch < 27) ? ap[ch] : vp[ch - 27];
            }
        }

        // ---- async-stage W slice 0 into OW0 (drained by the barrier below) ----
        stage_w(ws, pool + OW0, wave, lane);

        // ---- alpha + shuffle transmittance scan (waves 0,1) ----
        float alpha = 0.f, prod = 1.f, wr = 0.f;
        if (tid < NS) {
            float x  = sigma_g[rb + tid] - 10.f;
            float sp = (x > 20.f) ? x : log1pf(expf(x));
            alpha = 1.f - expf(-sp * dists_g[rb + tid] * 25.f);
            if (tid == NS - 1) alpha = 1.f;
            float tb = 1.f - alpha + 1e-10f;
            prod = tb;
            #pragma unroll
            for (int d = 1; d < 64; d <<= 1) {
                float v = __shfl_up(prod, d);
                if (lane >= d) prod *= v;
            }
            if (tid == 63) scanS = prod;
        }

        // ---- build X slice 0 (channels 0,1) ----
        build_x(pool + OX0, m_b, cl_b, pv[0]);
        __syncthreads();

        // finish weights: wr = alpha * T_exclusive
        if (tid < NS) {
            float prev = __shfl_up(prod, 1);
            float base = (lane == 0) ? 1.f : prev;
            float scale = (wave == 1) ? scanS : 1.f;
            wr = alpha * base * scale;
        }

        // ---- unified 19-slice K-loop: GEMM1 (0..14) + GEMM2 (15..18) ----
        const f32x4 vzero = {0.f, 0.f, 0.f, 0.f};
        f32x4 acc[4][4];
        #pragma unroll
        for (int mt = 0; mt < 4; ++mt)
            #pragma unroll
            for (int nt = 0; nt < 4; ++nt) acc[mt][nt] = vzero;

        #pragma unroll 1
        for (int i = 0; i < NSLICE; ++i) {
            if (i + 1 < NSLICE)                      // async-stage next W slice
                stage_w(ws + (i + 1) * 4096,
                        pool + ((((i + 1) & 1) == 0) ? OW0 : OW1), wave, lane);

            const u16* Wb = pool + (((i & 1) == 0) ? OW0 : OW1);
            // unified frag-order A source: X slice or h1 slice
            const u16* Asrc = (i < KS1)
                ? (pool + (((i & 1) == 0) ? OX0 : OX1))
                : (pool + OH1 + (i - KS1) * 4096);
            bf16x8 a[4];
            #pragma unroll
            for (int mt = 0; mt < 4; ++mt)
                a[mt] = *(const bf16x8*)(Asrc + ((wm * 4 + mt) * 64 + lane) * 8);
            #pragma unroll
            for (int nt = 0; nt < 4; ++nt) {
                bf16x8 b = *(const bf16x8*)(Wb + ((wn * 4 + nt) * 64 + lane) * 8);
                #pragma unroll
                for (int mt = 0; mt < 4; ++mt)
                    acc[mt][nt] = __builtin_amdgcn_mfma_f32_16x16x32_bf16(a[mt], b, acc[mt][nt], 0, 0, 0);
            }
            if (i < KS1 - 1) {                       // build X slice i+1 (ch 2i+2, 2i+3)
                u16* Xb = pool + ((((i + 1) & 1) == 0) ? OX0 : OX1);
                build_x(Xb, m_b, cl_b, pv[i + 1]);
            }
            if (i == KS1 - 1) {
                // all waves must finish slice-14 A-reads before h1 overwrites X
                __syncthreads();
                // epilogue 1: h1 = relu(acc + b1) -> OH1 (bf16, A-frag order)
                #pragma unroll
                for (int mt = 0; mt < 4; ++mt)
                    #pragma unroll
                    for (int nt = 0; nt < 4; ++nt) {
                        int col = wn * 64 + nt * 16 + l15;
                        #pragma unroll
                        for (int rr = 0; rr < 4; ++rr) {
                            int row = wm * 64 + mt * 16 + quad * 4 + rr;
                            pool[OH1 + afoff(row, col)] =
                                f2bf1(fmaxf(acc[mt][nt][rr] + b1r[nt], 0.f));
                        }
                        acc[mt][nt] = vzero;          // reset for GEMM2
                    }
            }
            __syncthreads();
        }

        // ---- epilogue 2: h2 = relu(acc + b2) -> overlays h1 (A-frag order) ----
        #pragma unroll
        for (int mt = 0; mt < 4; ++mt)
            #pragma unroll
            for (int nt = 0; nt < 4; ++nt) {
                int col = wn * 64 + nt * 16 + l15;
                #pragma unroll
                for (int rr = 0; rr < 4; ++rr) {
                    int row = wm * 64 + mt * 16 + quad * 4 + rr;
                    pool[OH1 + afoff(row, col)] =
                        f2bf1(fmaxf(acc[mt][nt][rr] + b2r[nt], 0.f));
                }
            }
        __syncthreads();

        // ---- layer 3 via MFMA: rgb = sigmoid(h2 @ W3 + b3) ----
        f32x4 acc3[2] = {vzero, vzero};
        #pragma unroll
        for (int mi = 0; mi < 2; ++mi) {
            int mtt = wn * 2 + mi;                   // waves split the 4 row-tiles
            #pragma unroll
            for (int ks = 0; ks < 4; ++ks) {
                bf16x8 a3 = *(const bf16x8*)(pool + OH1 + ks * 4096 +
                    ((wm * 4 + mtt) * 64 + lane) * 8);
                acc3[mi] = __builtin_amdgcn_mfma_f32_16x16x32_bf16(a3, w3fr[ks], acc3[mi], 0, 0, 0);
            }
        }
        if (l15 < 3) {
            #pragma unroll
            for (int mi = 0; mi < 2; ++mi) {
                int mtt = wn * 2 + mi;
                #pragma unroll
                for (int rr = 0; rr < 4; ++rr) {
                    int row = wm * 64 + mtt * 16 + quad * 4 + rr;
                    float v = acc3[mi][rr] + b3v;
                    part[row * 3 + l15] = 1.f / (1.f + expf(-v));
                }
            }
        }
        __syncthreads();

        // ---- weighted sum over samples ----
        float v0 = 0.f, v1 = 0.f, v2 = 0.f;
        if (tid < NS) {
            v0 = wr * part[tid * 3 + 0];
            v1 = wr * part[tid * 3 + 1];
            v2 = wr * part[tid * 3 + 2];
            #pragma unroll
            for (int d = 1; d < 64; d <<= 1) {
                v0 += __shfl_xor(v0, d);
                v1 += __shfl_xor(v1, d);
                v2 += __shfl_xor(v2, d);
            }
            if (lane == 0) {
                sum2[wave * 3 + 0] = v0;
                sum2[wave * 3 + 1] = v1;
                sum2[wave * 3 + 2] = v2;
            }
        }
        __syncthreads();
        if (tid == 0) {
            out_g[r * 3 + 0] = sum2[0] + sum2[3];
            out_g[r * 3 + 1] = sum2[1] + sum2[4];
            out_g[r * 3 + 2] = sum2[2] + sum2[5];
        }
        __syncthreads();
    }
}

extern "C" void kernel_launch(void* const* d_in, const int* in_sizes, int n_in,
                              void* d_out, int out_size, void* d_ws, size_t ws_size,
                              hipStream_t stream) {
    (void)in_sizes; (void)n_in; (void)out_size; (void)ws_size;
    const float* sigma = (const float*)d_in[0];
    const float* app   = (const float*)d_in[1];
    const float* view  = (const float*)d_in[2];
    const float* dists = (const float*)d_in[3];
    const float* W1    = (const float*)d_in[4];
    const float* b1    = (const float*)d_in[5];
    const float* W2    = (const float*)d_in[6];
    const float* b2    = (const float*)d_in[7];
    const float* W3    = (const float*)d_in[8];
    const float* b3    = (const float*)d_in[9];
    float* out = (float*)d_out;

    u16* ws = (u16*)d_ws;   // 61440 (W1r) + 16384 (W2r) + 2048 (W3r) u16 = 159744 B

    prep_kernel<<<312, 256, 0, stream>>>(W1, W2, W3, ws);
    render_kernel<<<NBLOCKS, 256, 0, stream>>>(sigma, app, view, dists,
                                               b1, b2, b3, ws, out);
}

// Round 10
// 217.771 us; speedup vs baseline: 1.0420x; 1.0420x over previous
//
#include <hip/hip_runtime.h>
#include <math.h>

typedef unsigned short u16;
using bf16x8 = __attribute__((ext_vector_type(8))) short;
using f32x4  = __attribute__((ext_vector_type(4))) float;

#define NS      128
#define RAYS_PER_BLOCK 2
#define NBLOCKS (4096 / RAYS_PER_BLOCK)   // 2048 blocks
#define KS1     15      // 30 channels * 16 slots = 480 K
#define NSLICE  19      // 15 (W1) + 4 (W2) unified W slices of 4096 u16

// LDS pool offsets (u16 units). X slices are in MFMA-A-frag order (4096 u16
// each, padless). h1/h2 (A-frag order, 32 KB) OVERLAY the X double-buffer;
// part[] overlays the W double-buffer after the K-loop.
#define OW0   0         // W buf 0: 4096 u16
#define OW1   4096      // W buf 1: 4096 u16
#define OX0   8192      // X slice buf 0: 4096 u16 (frag order)
#define OX1   12288     // X slice buf 1: 4096 u16
#define OH1   8192      // h1/h2 frag-order: 128*128 = 16384 u16 (overlays X0+X1)
#define POOLSZ 24576    // 49152 B -> 3 blocks/CU

__device__ __forceinline__ u16 f2bf(float f) {           // host-prep path only
    unsigned int i = __float_as_uint(f);
    return (u16)((i + 0x7FFFu + ((i >> 16) & 1u)) >> 16);  // RNE
}

// pack two floats to bf16 pair [hi:lo] in one dword (round half away + perm)
__device__ __forceinline__ unsigned pk(float hi, float lo) {
    unsigned a = __float_as_uint(hi) + 0x8000u;
    unsigned b = __float_as_uint(lo) + 0x8000u;
    return __builtin_amdgcn_perm(a, b, 0x07060302u);  // [a.hi16 : b.hi16]
}
__device__ __forceinline__ u16 f2bf1(float f) {
    return (u16)((__float_as_uint(f) + 0x8000u) >> 16);
}

// A-frag-order offset for a [128 x K] bf16 matrix (k-slices of 32 are 4096 u16
// each; a wave A-frag ds_read_b128 is lane-sequential, conflict-free):
__device__ __forceinline__ int afoff(int m, int k) {
    return ((((k >> 5) * 8 + (m >> 4)) * 64) + (((k >> 3) & 3) * 16) + (m & 15)) * 8 + (k & 7);
}

// async global->LDS copy of one 8 KB W slice (no VGPR round-trip).
__device__ __forceinline__ void stage_w(const u16* g, u16* l, int wave, int lane) {
    #pragma unroll
    for (int c = 0; c < 2; ++c) {
        const u16* gp = g + (wave * 2 + c) * 512 + lane * 8;
        u16* lp = l + (wave * 2 + c) * 512;
        __builtin_amdgcn_global_load_lds(
            (const __attribute__((address_space(1))) unsigned int*)gp,
            (__attribute__((address_space(3))) unsigned int*)lp, 16, 0, 0);
    }
}

// channel/slot -> original mlp_in k index (reference ordering)
__device__ __forceinline__ int orig_k(int ch, int slot) {
    if (ch < 27) {
        if (slot == 0) return ch;
        if (slot <= 6) return 30 + ch * 6 + (slot - 1);     // sin(app)
        return 192 + ch * 6 + (slot - 7);                    // cos(app)
    } else {
        int c = ch - 27;
        if (slot == 0) return 27 + c;
        if (slot <= 6) return 354 + c * 6 + (slot - 1);      // sin(view)
        return 372 + c * 6 + (slot - 7);                     // cos(view)
    }
}

// build one channel-half of a frag-order X slice: thread (m_b, cl_b) owns
// chunks 2cl_b, 2cl_b+1 of group g=m_b>>4; slots [v, sin f0..5, cos f0..5, 0x3]
__device__ __forceinline__ void build_x(u16* Xb, int m_b, int cl_b, float v) {
    float rev = v * 0.15915494309189535f;
    rev -= floorf(rev);
    float s0 = __builtin_amdgcn_sinf(rev);
    float c0 = __builtin_amdgcn_cosf(rev);
    float s1 = 2.f * s0 * c0, c1 = c0 * c0 - s0 * s0;
    float s2 = 2.f * s1 * c1, c2 = c1 * c1 - s1 * s1;
    float s3 = 2.f * s2 * c2, c3 = c2 * c2 - s2 * s2;
    float s4 = 2.f * s3 * c3, c4 = c3 * c3 - s3 * s3;
    float s5 = 2.f * s4 * c4, c5 = c4 * c4 - s4 * s4;
    uint4 lo, hi;
    lo.x = pk(s0, v);  lo.y = pk(s2, s1);  lo.z = pk(s4, s3);  lo.w = pk(c0, s5);
    hi.x = pk(c2, c1); hi.y = pk(c4, c3);  hi.z = pk(0.f, c5); hi.w = 0u;
    int base = (m_b >> 4) * 512 + ((2 * cl_b) * 16 + (m_b & 15)) * 8;
    *(uint4*)(Xb + base)       = lo;   // chunk 2*cl_b
    *(uint4*)(Xb + base + 128) = hi;   // chunk 2*cl_b+1 (+16*8 u16)
}

// W1 -> 15 slices, W2 -> 4 slices, W3 -> 4 mini B-frag slices (N padded 16)
__global__ __launch_bounds__(256) void prep_kernel(
    const float* __restrict__ W1, const float* __restrict__ W2,
    const float* __restrict__ W3, u16* __restrict__ ws)
{
    int idx = blockIdx.x * 256 + threadIdx.x;
    if (idx < 61440) {                               // W1r: [ks15][nt8][lane64][j8]
        int j = idx & 7, lane = (idx >> 3) & 63, nt = (idx >> 9) & 7, ks = idx >> 12;
        int q = lane >> 4, l15 = lane & 15;
        int klocal = q * 8 + j;                      // 0..31
        int ch = ks * 2 + (klocal >> 4);
        int slot = klocal & 15;
        int n = nt * 16 + l15;
        ws[idx] = (slot < 13) ? f2bf(W1[orig_k(ch, slot) * 128 + n]) : (u16)0;
    } else if (idx < 77824) {                        // W2r: [ks4][nt8][lane64][j8]
        int i2 = idx - 61440;
        int j = i2 & 7, lane = (i2 >> 3) & 63, nt = (i2 >> 9) & 7, ks = i2 >> 12;
        int k = ks * 32 + (lane >> 4) * 8 + j;
        int n = nt * 16 + (lane & 15);
        ws[idx] = f2bf(W2[k * 128 + n]);
    } else if (idx < 79872) {                        // W3r: [ks4][lane64][j8], N pad 16
        int i3 = idx - 77824;
        int j = i3 & 7, lane = (i3 >> 3) & 63, ks = i3 >> 9;
        int k = ks * 32 + (lane >> 4) * 8 + j;
        int n = lane & 15;
        ws[idx] = (n < 3) ? f2bf(W3[k * 3 + n]) : (u16)0;
    }
}

__global__ __launch_bounds__(256, 3) void render_kernel(
    const float* __restrict__ sigma_g, const float* __restrict__ app_g,
    const float* __restrict__ view_g,  const float* __restrict__ dists_g,
    const float* __restrict__ b1_g,    const float* __restrict__ b2_g,
    const float* __restrict__ b3_g,    const u16* __restrict__ ws,
    float* __restrict__ out_g)
{
    __shared__ __align__(16) u16 pool[POOLSZ];
    __shared__ float scanS;          // wave0 scan total broadcast
    __shared__ float sum2[6];        // per-wave final partials
    float* part = (float*)(pool + OW0);   // [NS*3] overlays W dbuf (dead post K-loop)

    const int tid  = threadIdx.x;
    const int lane = tid & 63;
    const int wave = tid >> 6;
    const int l15  = lane & 15;
    const int quad = lane >> 4;
    const int wm   = wave >> 1;      // row half
    const int wn   = wave & 1;       // col half

    const u16* w3r = ws + 77824;

    // per-kernel constants in registers
    float b1r[4], b2r[4];
    #pragma unroll
    for (int nt = 0; nt < 4; ++nt) {
        int col = wn * 64 + nt * 16 + l15;
        b1r[nt] = b1_g[col];
        b2r[nt] = b2_g[col];
    }
    const float b3v = (l15 < 3) ? b3_g[l15] : 0.f;
    bf16x8 w3fr[4];
    #pragma unroll
    for (int ks = 0; ks < 4; ++ks)
        w3fr[ks] = *(const bf16x8*)(w3r + (ks * 64 + lane) * 8);

    const int m_b  = tid >> 1;       // X-build row
    const int cl_b = tid & 1;        // X-build channel-local

    #pragma unroll 1
    for (int ri = 0; ri < RAYS_PER_BLOCK; ++ri) {
        const int r  = blockIdx.x * RAYS_PER_BLOCK + ri;
        const int rb = r * NS;
        const float* ap = app_g  + (rb + m_b) * 27;
        const float* vp = view_g + (rb + m_b) * 3;

        // ---- rolling input prefetch: only 2 values resident (no spill) ----
        float pv_cur = ap[cl_b];                       // ch = cl_b (slice 0)
        float pv_nxt = ap[2 + cl_b];                   // ch = 2+cl_b (slice 1)

        // ---- async-stage W slice 0 into OW0 (drained by the barrier below) ----
        stage_w(ws, pool + OW0, wave, lane);

        // ---- alpha + shuffle transmittance scan (waves 0,1) ----
        float alpha = 0.f, prod = 1.f, wr = 0.f;
        if (tid < NS) {
            float x  = sigma_g[rb + tid] - 10.f;
            float sp = (x > 20.f) ? x : log1pf(expf(x));
            alpha = 1.f - expf(-sp * dists_g[rb + tid] * 25.f);
            if (tid == NS - 1) alpha = 1.f;
            float tb = 1.f - alpha + 1e-10f;
            prod = tb;
            #pragma unroll
            for (int d = 1; d < 64; d <<= 1) {
                float v = __shfl_up(prod, d);
                if (lane >= d) prod *= v;
            }
            if (tid == 63) scanS = prod;
        }

        // ---- build X slice 0 (channels 0,1) ----
        build_x(pool + OX0, m_b, cl_b, pv_cur);
        pv_cur = pv_nxt;
        __syncthreads();

        // finish weights: wr = alpha * T_exclusive
        if (tid < NS) {
            float prev = __shfl_up(prod, 1);
            float base = (lane == 0) ? 1.f : prev;
            float scale = (wave == 1) ? scanS : 1.f;
            wr = alpha * base * scale;
        }

        // ---- unified 19-slice K-loop: GEMM1 (0..14) + GEMM2 (15..18) ----
        const f32x4 vzero = {0.f, 0.f, 0.f, 0.f};
        f32x4 acc[4][4];
        #pragma unroll
        for (int mt = 0; mt < 4; ++mt)
            #pragma unroll
            for (int nt = 0; nt < 4; ++nt) acc[mt][nt] = vzero;

        #pragma unroll 1
        for (int i = 0; i < NSLICE; ++i) {
            if (i + 1 < NSLICE)                      // async-stage next W slice
                stage_w(ws + (i + 1) * 4096,
                        pool + ((((i + 1) & 1) == 0) ? OW0 : OW1), wave, lane);
            if (i + 2 < KS1) {                       // issue input for slice i+2
                int ch = 2 * (i + 2) + cl_b;
                pv_nxt = (ch < 27) ? ap[ch] : vp[ch - 27];
            }

            const u16* Wb = pool + (((i & 1) == 0) ? OW0 : OW1);
            // unified frag-order A source: X slice or h1 slice
            const u16* Asrc = (i < KS1)
                ? (pool + (((i & 1) == 0) ? OX0 : OX1))
                : (pool + OH1 + (i - KS1) * 4096);
            bf16x8 a[4];
            #pragma unroll
            for (int mt = 0; mt < 4; ++mt)
                a[mt] = *(const bf16x8*)(Asrc + ((wm * 4 + mt) * 64 + lane) * 8);
            #pragma unroll
            for (int nt = 0; nt < 4; ++nt) {
                bf16x8 b = *(const bf16x8*)(Wb + ((wn * 4 + nt) * 64 + lane) * 8);
                #pragma unroll
                for (int mt = 0; mt < 4; ++mt)
                    acc[mt][nt] = __builtin_amdgcn_mfma_f32_16x16x32_bf16(a[mt], b, acc[mt][nt], 0, 0, 0);
            }
            if (i < KS1 - 1) {                       // build X slice i+1 (ch 2i+2, 2i+3)
                u16* Xb = pool + ((((i + 1) & 1) == 0) ? OX0 : OX1);
                build_x(Xb, m_b, cl_b, pv_cur);
                pv_cur = pv_nxt;
            }
            if (i == KS1 - 1) {
                // all waves must finish slice-14 A-reads before h1 overwrites X
                __syncthreads();
                // epilogue 1: h1 = relu(acc + b1) -> OH1 (bf16, A-frag order)
                #pragma unroll
                for (int mt = 0; mt < 4; ++mt)
                    #pragma unroll
                    for (int nt = 0; nt < 4; ++nt) {
                        int col = wn * 64 + nt * 16 + l15;
                        #pragma unroll
                        for (int rr = 0; rr < 4; ++rr) {
                            int row = wm * 64 + mt * 16 + quad * 4 + rr;
                            pool[OH1 + afoff(row, col)] =
                                f2bf1(fmaxf(acc[mt][nt][rr] + b1r[nt], 0.f));
                        }
                        acc[mt][nt] = vzero;          // reset for GEMM2
                    }
            }
            __syncthreads();
        }

        // ---- epilogue 2: h2 = relu(acc + b2) -> overlays h1 (A-frag order) ----
        #pragma unroll
        for (int mt = 0; mt < 4; ++mt)
            #pragma unroll
            for (int nt = 0; nt < 4; ++nt) {
                int col = wn * 64 + nt * 16 + l15;
                #pragma unroll
                for (int rr = 0; rr < 4; ++rr) {
                    int row = wm * 64 + mt * 16 + quad * 4 + rr;
                    pool[OH1 + afoff(row, col)] =
                        f2bf1(fmaxf(acc[mt][nt][rr] + b2r[nt], 0.f));
                }
            }
        __syncthreads();

        // ---- layer 3 via MFMA: rgb = sigmoid(h2 @ W3 + b3) ----
        f32x4 acc3[2] = {vzero, vzero};
        #pragma unroll
        for (int mi = 0; mi < 2; ++mi) {
            int mtt = wn * 2 + mi;                   // waves split the 4 row-tiles
            #pragma unroll
            for (int ks = 0; ks < 4; ++ks) {
                bf16x8 a3 = *(const bf16x8*)(pool + OH1 + ks * 4096 +
                    ((wm * 4 + mtt) * 64 + lane) * 8);
                acc3[mi] = __builtin_amdgcn_mfma_f32_16x16x32_bf16(a3, w3fr[ks], acc3[mi], 0, 0, 0);
            }
        }
        if (l15 < 3) {
            #pragma unroll
            for (int mi = 0; mi < 2; ++mi) {
                int mtt = wn * 2 + mi;
                #pragma unroll
                for (int rr = 0; rr < 4; ++rr) {
                    int row = wm * 64 + mtt * 16 + quad * 4 + rr;
                    float v = acc3[mi][rr] + b3v;
                    part[row * 3 + l15] = 1.f / (1.f + expf(-v));
                }
            }
        }
        __syncthreads();

        // ---- weighted sum over samples ----
        float v0 = 0.f, v1 = 0.f, v2 = 0.f;
        if (tid < NS) {
            v0 = wr * part[tid * 3 + 0];
            v1 = wr * part[tid * 3 + 1];
            v2 = wr * part[tid * 3 + 2];
            #pragma unroll
            for (int d = 1; d < 64; d <<= 1) {
                v0 += __shfl_xor(v0, d);
                v1 += __shfl_xor(v1, d);
                v2 += __shfl_xor(v2, d);
            }
            if (lane == 0) {
                sum2[wave * 3 + 0] = v0;
                sum2[wave * 3 + 1] = v1;
                sum2[wave * 3 + 2] = v2;
            }
        }
        __syncthreads();
        if (tid == 0) {
            out_g[r * 3 + 0] = sum2[0] + sum2[3];
            out_g[r * 3 + 1] = sum2[1] + sum2[4];
            out_g[r * 3 + 2] = sum2[2] + sum2[5];
        }
        __syncthreads();
    }
}

extern "C" void kernel_launch(void* const* d_in, const int* in_sizes, int n_in,
                              void* d_out, int out_size, void* d_ws, size_t ws_size,
                              hipStream_t stream) {
    (void)in_sizes; (void)n_in; (void)out_size; (void)ws_size;
    const float* sigma = (const float*)d_in[0];
    const float* app   = (const float*)d_in[1];
    const float* view  = (const float*)d_in[2];
    const float* dists = (const float*)d_in[3];
    const float* W1    = (const float*)d_in[4];
    const float* b1    = (const float*)d_in[5];
    const float* W2    = (const float*)d_in[6];
    const float* b2    = (const float*)d_in[7];
    const float* W3    = (const float*)d_in[8];
    const float* b3    = (const float*)d_in[9];
    float* out = (float*)d_out;

    u16* ws = (u16*)d_ws;   // 61440 (W1r) + 16384 (W2r) + 2048 (W3r) u16 = 159744 B

    prep_kernel<<<312, 256, 0, stream>>>(W1, W2, W3, ws);
    render_kernel<<<NBLOCKS, 256, 0, stream>>>(sigma, app, view, dists,
                                               b1, b2, b3, ws, out);
}